// Round 4
// baseline (471.648 us; speedup 1.0000x reference)
//
#include <hip/hip_runtime.h>

#define B 64
#define N 1025
#define C 768
#define H 12
#define HD 64
#define NCH 16          // n-chunks for the fused pass (64 rows each, last=65)

__device__ __forceinline__ float wave_reduce_add(float v) {
    #pragma unroll
    for (int m = 1; m < 64; m <<= 1) v += __shfl_xor(v, m, 64);
    return v;
}

#define FMA4(d, s, xv) { d.x += (s) * xv.x; d.y += (s) * xv.y; d.z += (s) * xv.z; d.w += (s) * xv.w; }

// ---------------------------------------------------------------------------
// k_qkf: fused q-projection + qk precompute for one (btile, head).
//   q[b][h*64+i] = 0.125*(cls[b].qW[h*64+i,:] + qb[..])      (stage 1, LDS)
//   qk[b][h][c'] = sum_i q[b][h*64+i] * kW[h*64+i][c']       (stage 2)
//   qkb[b][h]    = sum_i q[b][h*64+i] * kb[h*64+i]
// grid (16 btiles, 12 heads), block 256 (4 waves; wave w = batch bt*4+w).
// ---------------------------------------------------------------------------
__global__ __launch_bounds__(256) void k_qkf(const float* __restrict__ x,
                                             const float* __restrict__ qW,
                                             const float* __restrict__ qb,
                                             const float* __restrict__ kW,
                                             const float* __restrict__ kb,
                                             float* __restrict__ qk,
                                             float* __restrict__ qkb) {
    __shared__ __attribute__((aligned(16))) float cls[4 * C];   // 12 KB
    __shared__ float qv[4 * 64];                                // 1 KB
    int bt = blockIdx.x, h = blockIdx.y, tid = threadIdx.x;
    for (int i = tid; i < 768; i += 256) {       // 4 rows x 192 float4
        int bl = i / 192, c4 = i % 192;
        ((float4*)cls)[i] = ((const float4*)(x + (size_t)(bt * 4 + bl) * N * C))[c4];
    }
    __syncthreads();
    int w = tid >> 6, lane = tid & 63;
    const float* clsrow = &cls[w * C];
    for (int i = 0; i < 64; ++i) {
        int row = h * 64 + i;
        const float4* wr = (const float4*)(qW + (size_t)row * C + lane * 12);
        const float4* xr = (const float4*)(clsrow + lane * 12);
        float acc = 0.f;
        #pragma unroll
        for (int s = 0; s < 3; ++s) {
            float4 a = wr[s], v = xr[s];
            acc += a.x * v.x + a.y * v.y + a.z * v.z + a.w * v.w;
        }
        acc = wave_reduce_add(acc);
        if (lane == 0) qv[w * 64 + i] = 0.125f * (acc + qb[row]);
    }
    __syncthreads();
    if (tid < 192) {
        float4 acc[4] = {};
        for (int i = 0; i < 64; ++i) {
            float4 kv = *(const float4*)(kW + (size_t)(h * 64 + i) * C + tid * 4);
            #pragma unroll
            for (int bl = 0; bl < 4; ++bl) {
                float qq = qv[bl * 64 + i];
                FMA4(acc[bl], qq, kv);
            }
        }
        #pragma unroll
        for (int bl = 0; bl < 4; ++bl)
            *(float4*)(qk + ((size_t)(bt * 4 + bl) * H + h) * C + tid * 4) = acc[bl];
    }
    float vv = qv[w * 64 + lane] * kb[h * 64 + lane];
    vv = wave_reduce_add(vv);
    if (lane == 0) qkb[(bt * 4 + w) * H + h] = vv;
}

// ---------------------------------------------------------------------------
// k_fused: single x pass. Per (chunk k, batch b), rows nlo..nlo+nn-1:
//  A) scores s[h][n] = x[n,:].qk[b,h,:] into LDS (k_scores wave layout)
//  B) a1 = (s+qkb) + w1W@(s+qkb) + w1b; e = exp(a1) (no max needed, |a1|<~5);
//     S partial -> Sp
//  C) Ep[h][c] += e[h][n]*x[n][c]; Xp[c] += x[n][c]  (x re-read, L2/L3 hot)
// grid (16, 64), block 256. LDS ~40 KB -> 4 blocks/CU.
// ---------------------------------------------------------------------------
__global__ __launch_bounds__(256) void k_fused(const float* __restrict__ x,
                                               const float* __restrict__ qk,
                                               const float* __restrict__ qkb,
                                               const float* __restrict__ w1W,
                                               const float* __restrict__ w1b,
                                               float* __restrict__ Ep,
                                               float* __restrict__ Xp,
                                               float* __restrict__ Sp) {
    __shared__ __attribute__((aligned(16))) float qs[12 * C];   // 36 KB
    __shared__ __attribute__((aligned(16))) float et[66 * 12];  // scores -> e, [n][h]
    __shared__ float w1s[144], w1bs[12], qbs[12];
    __shared__ float sred[4][12];
    int k = blockIdx.x, b = blockIdx.y, tid = threadIdx.x;
    int nlo = k * 64, nn = (k == NCH - 1) ? 65 : 64;
    int rmax = nlo + nn;
    const float4* qksrc = (const float4*)(qk + (size_t)b * H * C);
    for (int i = tid; i < 2304; i += 256) ((float4*)qs)[i] = qksrc[i];
    if (tid < 144) w1s[tid] = w1W[tid];
    if (tid < 12)  { w1bs[tid] = w1b[tid]; qbs[tid] = qkb[b * 12 + tid]; }
    __syncthreads();

    // ---- stage A: scores into et ----
    int w = tid >> 6, lane = tid & 63;
    int c16 = lane & 15, r = lane >> 4;
    const float* xb = x + (size_t)b * N * C;
    for (int p = 0; p * 64 < nn; ++p) {
        int rowbase = nlo + p * 64 + w * 16 + r * 4;
        float acc[4][12] = {};
        for (int cc = 0; cc < C; cc += 128) {
            int c0 = cc + c16 * 4, c1 = c0 + 64;
            float4 xv0[4], xv1[4];
            #pragma unroll
            for (int j = 0; j < 4; ++j) {
                int row = rowbase + j;
                const float* xr = xb + (size_t)row * C;
                bool ok = row < rmax;
                xv0[j] = ok ? *(const float4*)(xr + c0) : make_float4(0.f,0.f,0.f,0.f);
                xv1[j] = ok ? *(const float4*)(xr + c1) : make_float4(0.f,0.f,0.f,0.f);
            }
            #pragma unroll
            for (int h = 0; h < 12; ++h) {
                float4 q0 = *(const float4*)(qs + h * C + c0);
                float4 q1 = *(const float4*)(qs + h * C + c1);
                #pragma unroll
                for (int j = 0; j < 4; ++j) {
                    acc[j][h] += xv0[j].x * q0.x + xv0[j].y * q0.y +
                                 xv0[j].z * q0.z + xv0[j].w * q0.w;
                    acc[j][h] += xv1[j].x * q1.x + xv1[j].y * q1.y +
                                 xv1[j].z * q1.z + xv1[j].w * q1.w;
                }
            }
        }
        #pragma unroll
        for (int j = 0; j < 4; ++j)
            #pragma unroll
            for (int h = 0; h < 12; ++h) {
                float v = acc[j][h];
                v += __shfl_xor(v, 1); v += __shfl_xor(v, 2);
                v += __shfl_xor(v, 4); v += __shfl_xor(v, 8);
                acc[j][h] = v;
            }
        if (c16 == 0) {
            #pragma unroll
            for (int j = 0; j < 4; ++j) {
                int row = rowbase + j;
                if (row < rmax) {
                    #pragma unroll
                    for (int h = 0; h < 12; ++h)
                        et[(row - nlo) * 12 + h] = acc[j][h];
                }
            }
        }
    }
    __syncthreads();

    // ---- stage B: mix1 + exp (in place, column-private) + S partial ----
    float e_[12];
    bool act = tid < nn;
    if (act) {
        float s_[12];
        #pragma unroll
        for (int h = 0; h < 12; ++h) s_[h] = et[tid * 12 + h] + qbs[h];
        #pragma unroll
        for (int g = 0; g < 12; ++g) {
            float a = s_[g] + w1bs[g];
            #pragma unroll
            for (int h = 0; h < 12; ++h) a += w1s[g * 12 + h] * s_[h];
            e_[g] = __expf(a);
        }
        #pragma unroll
        for (int g = 0; g < 12; ++g) et[tid * 12 + g] = e_[g];
    } else {
        #pragma unroll
        for (int g = 0; g < 12; ++g) e_[g] = 0.f;
    }
    #pragma unroll
    for (int g = 0; g < 12; ++g) {
        float v = wave_reduce_add(e_[g]);
        if (lane == 0) sred[w][g] = v;
    }
    __syncthreads();
    if (tid < 12)
        Sp[((size_t)b * NCH + k) * 12 + tid] =
            sred[0][tid] + sred[1][tid] + sred[2][tid] + sred[3][tid];

    // ---- stage C: E / X accumulation (192 threads own float4 columns) ----
    if (tid < 192) {
        const float* xr = x + ((size_t)b * N + nlo) * C + tid * 4;
        float4 Eacc[12] = {};
        float4 Xacc = make_float4(0.f, 0.f, 0.f, 0.f);
        for (int n = 0; n < nn; ++n) {
            float4 xv = *(const float4*)(xr + (size_t)n * C);
            const float4* ar = (const float4*)(et + n * 12);
            float4 a0 = ar[0], a1 = ar[1], a2 = ar[2];
            FMA4(Eacc[0], a0.x, xv); FMA4(Eacc[1], a0.y, xv); FMA4(Eacc[2], a0.z, xv); FMA4(Eacc[3], a0.w, xv);
            FMA4(Eacc[4], a1.x, xv); FMA4(Eacc[5], a1.y, xv); FMA4(Eacc[6], a1.z, xv); FMA4(Eacc[7], a1.w, xv);
            FMA4(Eacc[8], a2.x, xv); FMA4(Eacc[9], a2.y, xv); FMA4(Eacc[10], a2.z, xv); FMA4(Eacc[11], a2.w, xv);
            Xacc.x += xv.x; Xacc.y += xv.y; Xacc.z += xv.z; Xacc.w += xv.w;
        }
        #pragma unroll
        for (int h = 0; h < 12; ++h)
            *(float4*)(Ep + (((size_t)(k * B + b)) * H + h) * C + tid * 4) = Eacc[h];
        *(float4*)(Xp + ((size_t)(k * B + b)) * C + tid * 4) = Xacc;
    }
}

// ---------------------------------------------------------------------------
// k_comby: reduce chunk partials and apply softmax-normalize + mix2:
//   S[h] = sum_k Sp; E[h][c] = sum_k Ep; X[c] = sum_k Xp;
//   y[g][c] = E[g]/S[g] + sum_h w2[g,h]*E[h]/S[h] + w2b[g]*X[c]
// grid (4 c-quarters, 64 b), block 192 (thread owns scalar column c).
// ---------------------------------------------------------------------------
__global__ __launch_bounds__(192) void k_comby(const float* __restrict__ Ep,
                                               const float* __restrict__ Xp,
                                               const float* __restrict__ Sp,
                                               const float* __restrict__ w2W,
                                               const float* __restrict__ w2b,
                                               float* __restrict__ y) {
    __shared__ float is_[12], w2s[144], w2bs[12];
    int cq = blockIdx.x, b = blockIdx.y, tid = threadIdx.x;
    if (tid < 144) w2s[tid] = w2W[tid];
    if (tid < 12) {
        w2bs[tid] = w2b[tid];
        float S = 0.f;
        #pragma unroll
        for (int k = 0; k < NCH; ++k) S += Sp[((size_t)b * NCH + k) * 12 + tid];
        is_[tid] = 1.f / S;
    }
    __syncthreads();
    int c = cq * 192 + tid;
    float Eh[12] = {};
    float X = 0.f;
    for (int k = 0; k < NCH; ++k) {
        const float* base = Ep + ((size_t)(k * B + b)) * H * C + c;
        #pragma unroll
        for (int h = 0; h < 12; ++h) Eh[h] += base[(size_t)h * C];
        X += Xp[((size_t)(k * B + b)) * C + c];
    }
    #pragma unroll
    for (int h = 0; h < 12; ++h) Eh[h] *= is_[h];
    #pragma unroll
    for (int g = 0; g < 12; ++g) {
        float yv = Eh[g] + w2bs[g] * X;
        #pragma unroll
        for (int h = 0; h < 12; ++h) yv += w2s[g * 12 + h] * Eh[h];
        y[((size_t)b * H + g) * C + c] = yv;
    }
}

// ---------------------------------------------------------------------------
// k_zproj: z[b][c] = y[b,h(c),:] . vW[c,:] + vb[c]*sv,
// sv = 1 + rowsum(w2W)[h] + N*w2b[h] (softmax rows sum to 1 -> closed form).
// grid (16 btiles, 48 ctiles of 16; h = ct/4), block 256.
// ---------------------------------------------------------------------------
__global__ __launch_bounds__(256) void k_zproj(const float* __restrict__ y,
                                               const float* __restrict__ vW,
                                               const float* __restrict__ vb,
                                               const float* __restrict__ w2W,
                                               const float* __restrict__ w2b,
                                               float* __restrict__ z) {
    __shared__ __attribute__((aligned(16))) float ys[4 * C];
    int bt = blockIdx.x, ct = blockIdx.y, tid = threadIdx.x;
    int h = ct >> 2;
    for (int i = tid; i < 768; i += 256) {   // 4 rows x 192 float4
        int bl = i / 192, c4 = i % 192;
        ((float4*)ys)[i] = ((const float4*)(y + (((size_t)(bt * 4 + bl)) * H + h) * C))[c4];
    }
    __syncthreads();
    float sv = 1.f + 1025.f * w2b[h];
    #pragma unroll
    for (int j = 0; j < 12; ++j) sv += w2W[h * 12 + j];
    int w = tid >> 6, lane = tid & 63;
    int b = bt * 4 + w;
    const float* yrow = &ys[w * C];
    for (int cl = 0; cl < 16; ++cl) {
        int c = ct * 16 + cl;
        const float4* wr = (const float4*)(vW + (size_t)c * C + lane * 12);
        const float4* yr = (const float4*)(yrow + lane * 12);
        float acc = 0.f;
        #pragma unroll
        for (int s = 0; s < 3; ++s) {
            float4 a = wr[s], v = yr[s];
            acc += a.x * v.x + a.y * v.y + a.z * v.z + a.w * v.w;
        }
        acc = wave_reduce_add(acc);
        if (lane == 0) z[b * C + c] = acc + vb[c] * sv;
    }
}

// ---------------------------------------------------------------------------
// k_out: out[b][c] = z[b,:] . projW[c,:] + projb[c]
// grid (16 btiles, 48 ctiles of 16), block 256.
// ---------------------------------------------------------------------------
__global__ __launch_bounds__(256) void k_out(const float* __restrict__ z,
                                             const float* __restrict__ pW,
                                             const float* __restrict__ pb,
                                             float* __restrict__ out) {
    __shared__ __attribute__((aligned(16))) float zs[4 * C];
    int bt = blockIdx.x, ct = blockIdx.y, tid = threadIdx.x;
    for (int i = tid; i < 768; i += 256)
        ((float4*)zs)[i] = ((const float4*)(z + (size_t)bt * 4 * C))[i];
    __syncthreads();
    int w = tid >> 6, lane = tid & 63;
    int b = bt * 4 + w;
    for (int cl = 0; cl < 16; ++cl) {
        int c = ct * 16 + cl;
        const float4* wr = (const float4*)(pW + (size_t)c * C + lane * 12);
        const float4* zr = (const float4*)(zs + w * C + lane * 12);
        float acc = 0.f;
        #pragma unroll
        for (int s = 0; s < 3; ++s) {
            float4 a = wr[s], v = zr[s];
            acc += a.x * v.x + a.y * v.y + a.z * v.z + a.w * v.w;
        }
        acc = wave_reduce_add(acc);
        if (lane == 0) out[b * C + c] = acc + pb[c];
    }
}

extern "C" void kernel_launch(void* const* d_in, const int* in_sizes, int n_in,
                              void* d_out, int out_size, void* d_ws, size_t ws_size,
                              hipStream_t stream) {
    const float* x    = (const float*)d_in[0];
    const float* qW   = (const float*)d_in[1];
    const float* qb   = (const float*)d_in[2];
    const float* kW   = (const float*)d_in[3];
    const float* kb   = (const float*)d_in[4];
    const float* vW   = (const float*)d_in[5];
    const float* vb   = (const float*)d_in[6];
    const float* w1W  = (const float*)d_in[7];
    const float* w1b  = (const float*)d_in[8];
    const float* w2W  = (const float*)d_in[9];
    const float* w2b  = (const float*)d_in[10];
    const float* pW   = (const float*)d_in[11];
    const float* pb   = (const float*)d_in[12];
    float* out = (float*)d_out;

    float* ws  = (float*)d_ws;
    float* qk  = ws + 0;         // 64*12*768        =  589824
    float* qkb = ws + 589824;    // 64*12            =     768
    float* Ep  = ws + 590592;    // 16*64*12*768     = 9437184
    float* Xp  = ws + 10027776;  // 16*64*768        =  786432
    float* Sp  = ws + 10814208;  // 16*64*12         =   12288
    float* y   = ws + 10826496;  // 64*12*768        =  589824
    float* z   = ws + 11416320;  // 64*768           =   49152
    // total 11465472 floats = 45.9 MB

    k_qkf  <<<dim3(16, 12), 256, 0, stream>>>(x, qW, qb, kW, kb, qk, qkb);
    k_fused<<<dim3(NCH, 64), 256, 0, stream>>>(x, qk, qkb, w1W, w1b, Ep, Xp, Sp);
    k_comby<<<dim3(4, 64), 192, 0, stream>>>(Ep, Xp, Sp, w2W, w2b, y);
    k_zproj<<<dim3(16, 48), 256, 0, stream>>>(y, vW, vb, w2W, w2b, z);
    k_out  <<<dim3(16, 48), 256, 0, stream>>>(z, pW, pb, out);
}